// Round 6
// baseline (153.735 us; speedup 1.0000x reference)
//
#include <hip/hip_runtime.h>

typedef unsigned short u16;
typedef unsigned int u32;
using short8  = __attribute__((ext_vector_type(8))) short;
using floatx4 = __attribute__((ext_vector_type(4))) float;

#define N_TOK   2048
#define D_MODEL 1024
#define D_INT   512
#define NE      8

// ws layout (bytes)
#define O_TOK    0          // int tok[5120]
#define O_WROW   24576      // float wrow[5120]
#define O_XG     65536      // u16 Xg[5120*1024]
#define O_ACT    10551296   // u16 Act[5120*512]
#define O_FC1B   36765696   // u16 fc1b[8*1024*1024]
#define O_FC2B   53542912   // u16 fc2b[8*1024*512]

static __device__ inline u16 f2bf(float f) {
    u32 u = __builtin_bit_cast(u32, f);
    u = (u + 0x7fffu + ((u >> 16) & 1u)) >> 16;
    return (u16)u;
}
static __device__ inline u32 pack2(float a, float b) {
    return (u32)f2bf(a) | ((u32)f2bf(b) << 16);
}
static __device__ inline void glds16(const u16* g, u16* l) {
    __builtin_amdgcn_global_load_lds(
        (const __attribute__((address_space(1))) void*)g,
        (__attribute__((address_space(3))) void*)l, 16, 0, 0);
}

// Fused prep: [0,6144) convert weights f32->bf16; [6144,8192) route+gather one
// token each; [8192,8704) zero d_out. Row-pad quantum = 64.
__global__ __launch_bounds__(256) void prep_kernel(
    const float* __restrict__ x, const float* __restrict__ wts,
    const int* __restrict__ indices, const int* __restrict__ counts,
    const float* __restrict__ fc1, const float* __restrict__ fc2,
    u16* __restrict__ fc1b, u16* __restrict__ fc2b,
    u16* __restrict__ Xg, int* __restrict__ tok, float* __restrict__ wrow,
    float* __restrict__ out) {
    int b = blockIdx.x, tid = threadIdx.x;
    if (b < 6144) {
        size_t v = (size_t)b * 256 + tid;
        const float* src; u16* dst; size_t off;
        if (v < 1048576) { src = fc1; dst = fc1b; off = v * 8; }
        else             { src = fc2; dst = fc2b; off = (v - 1048576) * 8; }
        const floatx4* s4 = reinterpret_cast<const floatx4*>(src + off);
        floatx4 a = s4[0], bb = s4[1];
        uint4 o;
        o.x = pack2(a[0], a[1]); o.y = pack2(a[2], a[3]);
        o.z = pack2(bb[0], bb[1]); o.w = pack2(bb[2], bb[3]);
        *reinterpret_cast<uint4*>(dst + off) = o;
        return;
    }
    if (b < 8192) {
        int t = b - 6144;
        int off[NE];
        {
            int acc = 0;
            #pragma unroll
            for (int e = 0; e < NE; e++) { off[e] = acc; acc += ((counts[e] + 63) >> 6) << 6; }
        }
        int e0 = indices[2 * t], e1 = indices[2 * t + 1];
        __shared__ int s0, s1;
        if (tid == 0) { s0 = 0; s1 = 0; }
        __syncthreads();
        int c0 = 0, c1 = 0;
        const int4* ip = reinterpret_cast<const int4*>(indices);
        #pragma unroll
        for (int i = 0; i < 4; i++) {
            int4 vv = ip[tid * 4 + i];
            int q = tid * 16 + i * 4;
            c0 += (q + 0 < 2 * t && vv.x == e0) + (q + 1 < 2 * t && vv.y == e0)
                + (q + 2 < 2 * t && vv.z == e0) + (q + 3 < 2 * t && vv.w == e0);
            c1 += (q + 0 <= 2 * t && vv.x == e1) + (q + 1 <= 2 * t && vv.y == e1)
                + (q + 2 <= 2 * t && vv.z == e1) + (q + 3 <= 2 * t && vv.w == e1);
        }
        if (c0) atomicAdd(&s0, c0);
        if (c1) atomicAdd(&s1, c1);
        __syncthreads();
        int r0 = off[e0] + s0;
        int r1 = off[e1] + s1;
        if (tid == 0) {
            tok[r0] = t; tok[r1] = t;
            wrow[r0] = wts[2 * t]; wrow[r1] = wts[2 * t + 1];
        }
        const floatx4* src = reinterpret_cast<const floatx4*>(x + (size_t)t * D_MODEL);
        floatx4 a = src[tid];
        uint2 o;
        o.x = pack2(a[0], a[1]); o.y = pack2(a[2], a[3]);
        *reinterpret_cast<uint2*>(Xg + (size_t)r0 * D_MODEL + tid * 4) = o;
        *reinterpret_cast<uint2*>(Xg + (size_t)r1 * D_MODEL + tid * 4) = o;
        return;
    }
    {
        int z = b - 8192;
        floatx4* dst = reinterpret_cast<floatx4*>(out) + (size_t)z * 1024;
        #pragma unroll
        for (int i = 0; i < 4; i++) dst[i * 256 + tid] = (floatx4){0.f, 0.f, 0.f, 0.f};
        return;
    }
}

// GEMM1: 64-row x 64-g tile (y+z = 128 B-rows), BK=64, double-buffered LDS:
// one barrier per K-iter; next-iter glds16 issued before compute so the
// vmcnt(0)-at-barrier drain hides behind MFMA.
__global__ __launch_bounds__(256) void gemm1_kernel(
    const u16* __restrict__ Xg, const u16* __restrict__ fc1b,
    u16* __restrict__ Act, const int* __restrict__ counts) {
    __shared__ u16 As[2][64 * 64];
    __shared__ u16 Bs[2][128 * 64];
    int tid = threadIdx.x;
    int soff[NE + 1];
    {
        int acc = 0;
        #pragma unroll
        for (int e2 = 0; e2 < NE; e2++) { soff[e2] = acc; acc += ((counts[e2] + 63) >> 6) << 6; }
        soff[NE] = acc;
    }
    int row0 = blockIdx.y * 64;
    if (row0 >= soff[NE]) return;
    int e = 0;
    while (soff[e + 1] <= row0) e++;
    int bx = blockIdx.x;
    const u16* A  = Xg + (size_t)row0 * 1024;
    const u16* Be = fc1b + (size_t)e * 1024 * 1024;

    int lane = tid & 63, w = tid >> 6;
    int m0 = (w >> 1) * 32, n0 = (w & 1) * 32;
    int lr = lane & 15, kq = lane >> 4;

    const u16* gA[2]; int oA[2];
    #pragma unroll
    for (int j = 0; j < 2; j++) {
        int v = tid + j * 256;
        int r = v >> 3, kb = (v & 7) ^ (r & 7);
        gA[j] = A + (size_t)r * 1024 + kb * 8;
        oA[j] = (w * 64 + j * 256) * 8;
    }
    const u16* gB[4]; int oB[4];
    #pragma unroll
    for (int j = 0; j < 4; j++) {
        int v = tid + j * 256;
        int r = v >> 3, kb = (v & 7) ^ (r & 7);
        int grow = (r < 64) ? (bx * 64 + r) : (448 + bx * 64 + r);
        gB[j] = Be + (size_t)grow * 1024 + kb * 8;
        oB[j] = (w * 64 + j * 256) * 8;
    }

    floatx4 aY[2][2], aZ[2][2];
    #pragma unroll
    for (int i = 0; i < 2; i++)
        #pragma unroll
        for (int j = 0; j < 2; j++) {
            aY[i][j] = (floatx4){0.f, 0.f, 0.f, 0.f};
            aZ[i][j] = (floatx4){0.f, 0.f, 0.f, 0.f};
        }

    // prefetch k0=0 into buf 0
    glds16(gA[0], &As[0][oA[0]]); glds16(gA[1], &As[0][oA[1]]);
    glds16(gB[0], &Bs[0][oB[0]]); glds16(gB[1], &Bs[0][oB[1]]);
    glds16(gB[2], &Bs[0][oB[2]]); glds16(gB[3], &Bs[0][oB[3]]);
    __syncthreads();

    for (int k0 = 0; k0 < 1024; k0 += 64) {
        int buf = (k0 >> 6) & 1;
        int nk = k0 + 64;
        if (nk < 1024) {
            int nb = buf ^ 1;
            glds16(gA[0] + nk, &As[nb][oA[0]]); glds16(gA[1] + nk, &As[nb][oA[1]]);
            glds16(gB[0] + nk, &Bs[nb][oB[0]]); glds16(gB[1] + nk, &Bs[nb][oB[1]]);
            glds16(gB[2] + nk, &Bs[nb][oB[2]]); glds16(gB[3] + nk, &Bs[nb][oB[3]]);
        }
        #pragma unroll
        for (int ks = 0; ks < 2; ks++) {
            int sw = ((ks * 4 + kq) ^ (lr & 7)) * 8;
            short8 af[2], by[2], bz[2];
            #pragma unroll
            for (int i = 0; i < 2; i++)
                af[i] = *reinterpret_cast<const short8*>(&As[buf][(m0 + i * 16 + lr) * 64 + sw]);
            #pragma unroll
            for (int j = 0; j < 2; j++) {
                by[j] = *reinterpret_cast<const short8*>(&Bs[buf][(n0 + j * 16 + lr) * 64 + sw]);
                bz[j] = *reinterpret_cast<const short8*>(&Bs[buf][(64 + n0 + j * 16 + lr) * 64 + sw]);
            }
            #pragma unroll
            for (int i = 0; i < 2; i++)
                #pragma unroll
                for (int j = 0; j < 2; j++) {
                    aY[i][j] = __builtin_amdgcn_mfma_f32_16x16x32_bf16(af[i], by[j], aY[i][j], 0, 0, 0);
                    aZ[i][j] = __builtin_amdgcn_mfma_f32_16x16x32_bf16(af[i], bz[j], aZ[i][j], 0, 0, 0);
                }
        }
        __syncthreads();
    }
    #pragma unroll
    for (int i = 0; i < 2; i++)
        #pragma unroll
        for (int j = 0; j < 2; j++) {
            floatx4 y = aY[i][j], z = aZ[i][j];
            #pragma unroll
            for (int r = 0; r < 4; r++) {
                float zz = z[r];
                float av = y[r] * (zz / (1.0f + __expf(-zz)));
                int m = m0 + i * 16 + kq * 4 + r;
                int g = bx * 64 + n0 + j * 16 + lr;
                Act[(size_t)(row0 + m) * D_INT + g] = f2bf(av);
            }
        }
}

// GEMM2: 64-row x 128-d tile, BK=64, double-buffered; fused combine via f32 atomics.
__global__ __launch_bounds__(256) void gemm2_kernel(
    const u16* __restrict__ Act, const u16* __restrict__ fc2b,
    float* __restrict__ out, const int* __restrict__ counts,
    const int* __restrict__ tok, const float* __restrict__ wrow) {
    __shared__ u16 As[2][64 * 64];
    __shared__ u16 Bs[2][128 * 64];
    __shared__ int sTok[64];
    __shared__ float sW[64];
    int tid = threadIdx.x;
    int soff[NE + 1];
    {
        int acc = 0;
        #pragma unroll
        for (int e2 = 0; e2 < NE; e2++) { soff[e2] = acc; acc += ((counts[e2] + 63) >> 6) << 6; }
        soff[NE] = acc;
    }
    int row0 = blockIdx.y * 64;
    if (row0 >= soff[NE]) return;
    int e = 0;
    while (soff[e + 1] <= row0) e++;
    int bx = blockIdx.x;
    const u16* A  = Act + (size_t)row0 * 512;
    const u16* Be = fc2b + (size_t)e * 1024 * 512;

    int lane = tid & 63, w = tid >> 6;
    int m0 = (w >> 1) * 32, n0 = (w & 1) * 64;
    int lr = lane & 15, kq = lane >> 4;

    const u16* gA[2]; int oA[2];
    #pragma unroll
    for (int j = 0; j < 2; j++) {
        int v = tid + j * 256;
        int r = v >> 3, kb = (v & 7) ^ (r & 7);
        gA[j] = A + (size_t)r * 512 + kb * 8;
        oA[j] = (w * 64 + j * 256) * 8;
    }
    const u16* gB[4]; int oB[4];
    #pragma unroll
    for (int j = 0; j < 4; j++) {
        int v = tid + j * 256;
        int r = v >> 3, kb = (v & 7) ^ (r & 7);
        gB[j] = Be + (size_t)(bx * 128 + r) * 512 + kb * 8;
        oB[j] = (w * 64 + j * 256) * 8;
    }

    floatx4 acc[2][4];
    #pragma unroll
    for (int i = 0; i < 2; i++)
        #pragma unroll
        for (int j = 0; j < 4; j++) acc[i][j] = (floatx4){0.f, 0.f, 0.f, 0.f};

    glds16(gA[0], &As[0][oA[0]]); glds16(gA[1], &As[0][oA[1]]);
    glds16(gB[0], &Bs[0][oB[0]]); glds16(gB[1], &Bs[0][oB[1]]);
    glds16(gB[2], &Bs[0][oB[2]]); glds16(gB[3], &Bs[0][oB[3]]);
    __syncthreads();

    for (int k0 = 0; k0 < 512; k0 += 64) {
        int buf = (k0 >> 6) & 1;
        int nk = k0 + 64;
        if (nk < 512) {
            int nb = buf ^ 1;
            glds16(gA[0] + nk, &As[nb][oA[0]]); glds16(gA[1] + nk, &As[nb][oA[1]]);
            glds16(gB[0] + nk, &Bs[nb][oB[0]]); glds16(gB[1] + nk, &Bs[nb][oB[1]]);
            glds16(gB[2] + nk, &Bs[nb][oB[2]]); glds16(gB[3] + nk, &Bs[nb][oB[3]]);
        }
        #pragma unroll
        for (int ks = 0; ks < 2; ks++) {
            int sw = ((ks * 4 + kq) ^ (lr & 7)) * 8;
            short8 af[2], bf[4];
            #pragma unroll
            for (int i = 0; i < 2; i++)
                af[i] = *reinterpret_cast<const short8*>(&As[buf][(m0 + i * 16 + lr) * 64 + sw]);
            #pragma unroll
            for (int j = 0; j < 4; j++)
                bf[j] = *reinterpret_cast<const short8*>(&Bs[buf][(n0 + j * 16 + lr) * 64 + sw]);
            #pragma unroll
            for (int i = 0; i < 2; i++)
                #pragma unroll
                for (int j = 0; j < 4; j++)
                    acc[i][j] = __builtin_amdgcn_mfma_f32_16x16x32_bf16(af[i], bf[j], acc[i][j], 0, 0, 0);
        }
        __syncthreads();
    }
    if (tid < 64) {
        int g = row0 + tid;
        bool val = (g - soff[e]) < counts[e];
        sTok[tid] = val ? tok[g] : -1;
        sW[tid]   = val ? wrow[g] : 0.f;
    }
    __syncthreads();
    #pragma unroll
    for (int i = 0; i < 2; i++)
        #pragma unroll
        for (int r = 0; r < 4; r++) {
            int m = m0 + i * 16 + kq * 4 + r;
            int t = sTok[m];
            if (t >= 0) {
                float wgt = sW[m];
                float* dst = out + (size_t)t * D_MODEL + bx * 128;
                #pragma unroll
                for (int j = 0; j < 4; j++)
                    atomicAdd(dst + n0 + j * 16 + lr, wgt * acc[i][j][r]);
            }
        }
}

extern "C" void kernel_launch(void* const* d_in, const int* in_sizes, int n_in,
                              void* d_out, int out_size, void* d_ws, size_t ws_size,
                              hipStream_t stream) {
    const float* x       = (const float*)d_in[0];
    const float* wts     = (const float*)d_in[1];
    const int*   indices = (const int*)d_in[2];
    const int*   counts  = (const int*)d_in[3];
    const float* fc1     = (const float*)d_in[4];
    const float* fc2     = (const float*)d_in[5];
    float* out = (float*)d_out;
    char* ws = (char*)d_ws;

    int*   tok  = (int*)(ws + O_TOK);
    float* wrow = (float*)(ws + O_WROW);
    u16*   Xg   = (u16*)(ws + O_XG);
    u16*   Act  = (u16*)(ws + O_ACT);
    u16*   fc1b = (u16*)(ws + O_FC1B);
    u16*   fc2b = (u16*)(ws + O_FC2B);

    prep_kernel<<<8704, 256, 0, stream>>>(x, wts, indices, counts, fc1, fc2,
                                          fc1b, fc2b, Xg, tok, wrow, out);
    gemm1_kernel<<<dim3(8, 72), 256, 0, stream>>>(Xg, fc1b, Act, counts);
    gemm2_kernel<<<dim3(8, 72), 256, 0, stream>>>(Act, fc2b, out, counts, tok, wrow);
}